// Round 1
// baseline (372.632 us; speedup 1.0000x reference)
//
#include <hip/hip_runtime.h>

// ---------------- types ----------------
typedef __bf16 bf16x8 __attribute__((ext_vector_type(8)));
typedef float  f32x4  __attribute__((ext_vector_type(4)));

static __device__ __forceinline__ ushort f2bf(float f) {
    union { float f; unsigned u; } a; a.f = f;
    unsigned r = a.u + 0x7FFFu + ((a.u >> 16) & 1u);   // RNE
    return (ushort)(r >> 16);
}

// ---------------- constants ----------------
#define TS  2048   // S
#define TD  1024   // D
#define TL  256    // L
#define TH  1024   // H
#define TNH 16
#define THD 64
#define TDF 4096   // 4*D

// ---------------- weight transpose + f32->bf16 ----------------
// in: f32 [K][N] row-major, out: bf16(ushort) [N][K]
__global__ __launch_bounds__(256) void transpose_to_bf16(
    const float* __restrict__ in, ushort* __restrict__ out, int K, int N)
{
    __shared__ float tile[32][33];
    const int k0 = blockIdx.x * 32, n0 = blockIdx.y * 32;
    const int tx = threadIdx.x, ty = threadIdx.y;   // block (32,8)
#pragma unroll
    for (int i = ty; i < 32; i += 8)
        tile[i][tx] = in[(size_t)(k0 + i) * N + n0 + tx];
    __syncthreads();
#pragma unroll
    for (int i = ty; i < 32; i += 8)
        out[(size_t)(n0 + i) * K + k0 + tx] = f2bf(tile[tx][i]);
}

// ---------------- RMSNorm: f32 in -> bf16 out (D=1024, 256 thr/row) ----------------
__global__ __launch_bounds__(256) void rmsnorm_kernel(
    const float* __restrict__ x, const float* __restrict__ g,
    ushort* __restrict__ out, int D)
{
    const int row = blockIdx.x;
    const int tid = threadIdx.x;
    const float4 v = ((const float4*)(x + (size_t)row * D))[tid];
    float ss = v.x * v.x + v.y * v.y + v.z * v.z + v.w * v.w;
#pragma unroll
    for (int off = 32; off > 0; off >>= 1) ss += __shfl_down(ss, off);
    __shared__ float sums[4];
    if ((tid & 63) == 0) sums[tid >> 6] = ss;
    __syncthreads();
    const float tot = sums[0] + sums[1] + sums[2] + sums[3];
    const float scale = rsqrtf(tot / (float)D + 1e-6f);
    const float4 gv = ((const float4*)g)[tid];
    ushort4 o;
    o.x = f2bf(v.x * scale * gv.x);
    o.y = f2bf(v.y * scale * gv.y);
    o.z = f2bf(v.z * scale * gv.z);
    o.w = f2bf(v.w * scale * gv.w);
    *(ushort4*)(out + (size_t)row * D + tid * 4) = o;
}

// ---------------- bf16 GEMM: C[M,N] = A[M,K] @ BT[N,K]^T + bias, epilogue ----------------
// EPI: 0 = bf16 out; 1 = silu -> bf16 out; 2 = +resid -> f32 out; 3 = silu + resid -> f32 out
template <int EPI>
__global__ __launch_bounds__(256) void gemm_bf16_kernel(
    const ushort* __restrict__ A, const ushort* __restrict__ BT,
    const float* __restrict__ bias, const float* __restrict__ resid,
    void* __restrict__ outp, int M, int N, int K)
{
    constexpr int BK = 32;
    __shared__ alignas(16) ushort As[128 * BK];
    __shared__ alignas(16) ushort Bs[128 * BK];
    const int bm = blockIdx.y * 128, bn = blockIdx.x * 128;
    const int tid = threadIdx.x;
    const int lane = tid & 63, wave = tid >> 6;
    const int wr = (wave >> 1) * 64, wc = (wave & 1) * 64;
    const int l15 = lane & 15, l4 = lane >> 4;

    f32x4 acc[4][4] = {};

    const int sr = tid >> 2, sc = (tid & 3) * 8;      // staging: 2x16B per thread per tile
    const ushort* Ag = A + (size_t)(bm + sr) * K + sc;
    const ushort* Bg = BT + (size_t)(bn + sr) * K + sc;

    for (int k0 = 0; k0 < K; k0 += BK) {
        const uint4 a0 = *(const uint4*)(Ag + k0);
        const uint4 a1 = *(const uint4*)(Ag + (size_t)64 * K + k0);
        const uint4 b0 = *(const uint4*)(Bg + k0);
        const uint4 b1 = *(const uint4*)(Bg + (size_t)64 * K + k0);
        *(uint4*)&As[sr * BK + sc] = a0;
        *(uint4*)&As[(sr + 64) * BK + sc] = a1;
        *(uint4*)&Bs[sr * BK + sc] = b0;
        *(uint4*)&Bs[(sr + 64) * BK + sc] = b1;
        __syncthreads();

        bf16x8 af[4], bf[4];
#pragma unroll
        for (int mt = 0; mt < 4; ++mt)
            af[mt] = *(const bf16x8*)&As[(wr + mt * 16 + l15) * BK + l4 * 8];
#pragma unroll
        for (int nt = 0; nt < 4; ++nt)
            bf[nt] = *(const bf16x8*)&Bs[(wc + nt * 16 + l15) * BK + l4 * 8];
#pragma unroll
        for (int mt = 0; mt < 4; ++mt)
#pragma unroll
            for (int nt = 0; nt < 4; ++nt)
                acc[mt][nt] = __builtin_amdgcn_mfma_f32_16x16x32_bf16(
                    af[mt], bf[nt], acc[mt][nt], 0, 0, 0);
        __syncthreads();
    }

#pragma unroll
    for (int mt = 0; mt < 4; ++mt) {
#pragma unroll
        for (int nt = 0; nt < 4; ++nt) {
#pragma unroll
            for (int i = 0; i < 4; ++i) {
                const int row = bm + wr + mt * 16 + l4 * 4 + i;
                const int col = bn + wc + nt * 16 + l15;
                float v = acc[mt][nt][i] + bias[col];
                if constexpr (EPI == 1 || EPI == 3) v = v / (1.f + __expf(-v));  // silu
                if constexpr (EPI == 2 || EPI == 3) v += resid[(size_t)row * N + col];
                if constexpr (EPI == 0 || EPI == 1)
                    ((ushort*)outp)[(size_t)row * N + col] = f2bf(v);
                else
                    ((float*)outp)[(size_t)row * N + col] = v;
            }
        }
    }
}

// ---------------- causal flash attention (MLA), 16 heads, HD=64 ----------------
// grid: (S/64, NH); block 256 (4 waves x 16 q-rows). Q,K,V,O bf16 [S][NH*HD]
__global__ __launch_bounds__(256) void mla_attn_kernel(
    const ushort* __restrict__ Q, const ushort* __restrict__ Kg,
    const ushort* __restrict__ Vg, ushort* __restrict__ O)
{
    constexpr int NHHD = TNH * THD;   // 1024
    __shared__ alignas(16) ushort Ks[64 * 64];    // [key][d]
    __shared__ alignas(16) ushort VTs[64 * 64];   // [d][key]
    __shared__ alignas(16) ushort Ps[4][16 * 64]; // per-wave [row][key]
    const int qb = blockIdx.x, h = blockIdx.y;
    const int tid = threadIdx.x, lane = tid & 63, wave = tid >> 6;
    const int l15 = lane & 15, l4 = lane >> 4;
    const int qrow0 = qb * 64 + wave * 16;

    bf16x8 qf[2];
#pragma unroll
    for (int ks = 0; ks < 2; ++ks)
        qf[ks] = *(const bf16x8*)&Q[(size_t)(qrow0 + l15) * NHHD + h * THD + ks * 32 + l4 * 8];

    f32x4 oacc[4] = {};
    float m_run[4], l_run[4];
#pragma unroll
    for (int i = 0; i < 4; ++i) { m_run[i] = -1e30f; l_run[i] = 0.f; }

    const int sr = tid >> 3, sc = (tid & 7) * 8;  // staging coords

    for (int kt = 0; kt <= qb; ++kt) {
        // ---- stage K tile and V^T tile ----
        const ushort* kp = Kg + (size_t)(kt * 64 + sr) * NHHD + h * THD + sc;
        const uint4 k0v = *(const uint4*)kp;
        const uint4 k1v = *(const uint4*)(kp + (size_t)32 * NHHD);
        *(uint4*)&Ks[sr * 64 + sc] = k0v;
        *(uint4*)&Ks[(sr + 32) * 64 + sc] = k1v;
        const ushort* vp = Vg + (size_t)(kt * 64 + sr) * NHHD + h * THD + sc;
        const uint4 v0 = *(const uint4*)vp;
        const uint4 v1 = *(const uint4*)(vp + (size_t)32 * NHHD);
        const ushort* p0 = (const ushort*)&v0;
        const ushort* p1 = (const ushort*)&v1;
#pragma unroll
        for (int j = 0; j < 8; ++j) {
            VTs[(sc + j) * 64 + sr] = p0[j];
            VTs[(sc + j) * 64 + sr + 32] = p1[j];
        }
        __syncthreads();

        // ---- scores: s[nt] = Q @ K^T  (16 rows x 64 keys) ----
        f32x4 s[4] = {};
#pragma unroll
        for (int ks = 0; ks < 2; ++ks) {
#pragma unroll
            for (int nt = 0; nt < 4; ++nt) {
                const bf16x8 kf = *(const bf16x8*)&Ks[(nt * 16 + l15) * 64 + ks * 32 + l4 * 8];
                s[nt] = __builtin_amdgcn_mfma_f32_16x16x32_bf16(qf[ks], kf, s[nt], 0, 0, 0);
            }
        }

        const int kb = kt * 64;
        const bool diag = (kt == qb);
#pragma unroll
        for (int i = 0; i < 4; ++i) {
            const int qrow = qrow0 + l4 * 4 + i;
            float mx = m_run[i];
#pragma unroll
            for (int nt = 0; nt < 4; ++nt) {
                float v = s[nt][i] * 0.125f;
                if (diag && (kb + nt * 16 + l15 > qrow)) v = -1e30f;
                s[nt][i] = v;
                mx = fmaxf(mx, v);
            }
#pragma unroll
            for (int d = 1; d < 16; d <<= 1) mx = fmaxf(mx, __shfl_xor(mx, d));
            const float alpha = __expf(m_run[i] - mx);
            l_run[i] *= alpha;
#pragma unroll
            for (int nt = 0; nt < 4; ++nt) oacc[nt][i] *= alpha;
            float ps = 0.f;
#pragma unroll
            for (int nt = 0; nt < 4; ++nt) {
                const float p = __expf(s[nt][i] - mx);
                s[nt][i] = p;
                ps += p;
            }
#pragma unroll
            for (int d = 1; d < 16; d <<= 1) ps += __shfl_xor(ps, d);
            l_run[i] += ps;
            m_run[i] = mx;
#pragma unroll
            for (int nt = 0; nt < 4; ++nt)
                Ps[wave][(l4 * 4 + i) * 64 + nt * 16 + l15] = f2bf(s[nt][i]);
        }

        // ---- PV: oacc += P @ V ----
#pragma unroll
        for (int ks = 0; ks < 2; ++ks) {
            const bf16x8 pf = *(const bf16x8*)&Ps[wave][l15 * 64 + ks * 32 + l4 * 8];
#pragma unroll
            for (int dt = 0; dt < 4; ++dt) {
                const bf16x8 vf = *(const bf16x8*)&VTs[(dt * 16 + l15) * 64 + ks * 32 + l4 * 8];
                oacc[dt] = __builtin_amdgcn_mfma_f32_16x16x32_bf16(pf, vf, oacc[dt], 0, 0, 0);
            }
        }
        __syncthreads();
    }

#pragma unroll
    for (int dt = 0; dt < 4; ++dt)
#pragma unroll
        for (int i = 0; i < 4; ++i) {
            const int qrow = qrow0 + l4 * 4 + i;
            const float v = oacc[dt][i] / l_run[i];
            O[(size_t)qrow * NHHD + h * THD + dt * 16 + l15] = f2bf(v);
        }
}

// ---------------- launch ----------------
extern "C" void kernel_launch(void* const* d_in, const int* in_sizes, int n_in,
                              void* d_out, int out_size, void* d_ws, size_t ws_size,
                              hipStream_t stream)
{
    const float* x     = (const float*)d_in[0];
    const float* g1    = (const float*)d_in[1];
    const float* Wq    = (const float*)d_in[2];
    const float* bq    = (const float*)d_in[3];
    const float* Wdown = (const float*)d_in[4];
    const float* bdown = (const float*)d_in[5];
    const float* Wk    = (const float*)d_in[6];
    const float* bk    = (const float*)d_in[7];
    const float* Wv    = (const float*)d_in[8];
    const float* bv    = (const float*)d_in[9];
    const float* Wo    = (const float*)d_in[10];
    const float* bo    = (const float*)d_in[11];
    const float* g2    = (const float*)d_in[12];
    const float* W1    = (const float*)d_in[13];
    const float* b1    = (const float*)d_in[14];
    const float* W2    = (const float*)d_in[15];
    const float* b2    = (const float*)d_in[16];
    float* out = (float*)d_out;

    char* ws = (char*)d_ws;
    size_t off = 0;
    auto alloc = [&](size_t bytes) {
        void* p = ws + off;
        off += (bytes + 255) & ~(size_t)255;
        return p;
    };
    ushort* WqT    = (ushort*)alloc((size_t)TH * TD * 2);
    ushort* WdownT = (ushort*)alloc((size_t)TL * TD * 2);
    ushort* WkT    = (ushort*)alloc((size_t)TH * TL * 2);
    ushort* WvT    = (ushort*)alloc((size_t)TH * TL * 2);
    ushort* WoT    = (ushort*)alloc((size_t)TD * TH * 2);
    ushort* W1T    = (ushort*)alloc((size_t)TDF * TD * 2);
    ushort* W2T    = (ushort*)alloc((size_t)TD * TDF * 2);
    ushort* hbuf   = (ushort*)alloc((size_t)TS * TD * 2);
    ushort* cbuf   = (ushort*)alloc((size_t)TS * TL * 2);
    ushort* qbuf   = (ushort*)alloc((size_t)TS * TH * 2);
    ushort* kbuf   = (ushort*)alloc((size_t)TS * TH * 2);
    ushort* vbuf   = (ushort*)alloc((size_t)TS * TH * 2);
    ushort* obuf   = (ushort*)alloc((size_t)TS * TH * 2);
    float*  strm   = (float*)alloc((size_t)TS * TD * 4);
    ushort* h2buf  = (ushort*)alloc((size_t)TS * TD * 2);
    ushort* ffn1   = (ushort*)alloc((size_t)TS * TDF * 2);

    const dim3 tb(32, 8);
    transpose_to_bf16<<<dim3(TD / 32, TH / 32), tb, 0, stream>>>(Wq, WqT, TD, TH);
    transpose_to_bf16<<<dim3(TD / 32, TL / 32), tb, 0, stream>>>(Wdown, WdownT, TD, TL);
    transpose_to_bf16<<<dim3(TL / 32, TH / 32), tb, 0, stream>>>(Wk, WkT, TL, TH);
    transpose_to_bf16<<<dim3(TL / 32, TH / 32), tb, 0, stream>>>(Wv, WvT, TL, TH);
    transpose_to_bf16<<<dim3(TH / 32, TD / 32), tb, 0, stream>>>(Wo, WoT, TH, TD);
    transpose_to_bf16<<<dim3(TD / 32, TDF / 32), tb, 0, stream>>>(W1, W1T, TD, TDF);
    transpose_to_bf16<<<dim3(TDF / 32, TD / 32), tb, 0, stream>>>(W2, W2T, TDF, TD);

    rmsnorm_kernel<<<TS, 256, 0, stream>>>(x, g1, hbuf, TD);

    gemm_bf16_kernel<0><<<dim3(TH / 128, TS / 128), 256, 0, stream>>>(
        hbuf, WqT, bq, nullptr, qbuf, TS, TH, TD);
    gemm_bf16_kernel<0><<<dim3(TL / 128, TS / 128), 256, 0, stream>>>(
        hbuf, WdownT, bdown, nullptr, cbuf, TS, TL, TD);
    gemm_bf16_kernel<0><<<dim3(TH / 128, TS / 128), 256, 0, stream>>>(
        cbuf, WkT, bk, nullptr, kbuf, TS, TH, TL);
    gemm_bf16_kernel<0><<<dim3(TH / 128, TS / 128), 256, 0, stream>>>(
        cbuf, WvT, bv, nullptr, vbuf, TS, TH, TL);

    mla_attn_kernel<<<dim3(TS / 64, TNH), 256, 0, stream>>>(qbuf, kbuf, vbuf, obuf);

    gemm_bf16_kernel<2><<<dim3(TD / 128, TS / 128), 256, 0, stream>>>(
        obuf, WoT, bo, x, strm, TS, TD, TH);

    rmsnorm_kernel<<<TS, 256, 0, stream>>>(strm, g2, h2buf, TD);

    gemm_bf16_kernel<1><<<dim3(TDF / 128, TS / 128), 256, 0, stream>>>(
        h2buf, W1T, b1, nullptr, ffn1, TS, TDF, TD);
    gemm_bf16_kernel<3><<<dim3(TD / 128, TS / 128), 256, 0, stream>>>(
        ffn1, W2T, b2, strm, out, TS, TD, TDF);
}

// Round 2
// 335.756 us; speedup vs baseline: 1.1098x; 1.1098x over previous
//
#include <hip/hip_runtime.h>

// ---------------- types ----------------
typedef __bf16 bf16x8 __attribute__((ext_vector_type(8)));
typedef float  f32x4  __attribute__((ext_vector_type(4)));

static __device__ __forceinline__ ushort f2bf(float f) {
    union { float f; unsigned u; } a; a.f = f;
    unsigned r = a.u + 0x7FFFu + ((a.u >> 16) & 1u);   // RNE
    return (ushort)(r >> 16);
}

// ---------------- constants ----------------
#define TS  2048   // S
#define TD  1024   // D
#define TL  256    // L
#define TH  1024   // H
#define TNH 16
#define THD 64
#define TDF 4096   // 4*D

// LDS swizzle helpers for 128-byte-row tiles (row = 64 bf16).
// XOR bits 4-6 of the intra-row byte offset -> bijective, keeps 16B blocks.
static __device__ __forceinline__ ushort* swzp_hi(ushort* base, int row, int colbyte) {
    return (ushort*)((char*)base + row * 128 + (colbyte ^ (((row >> 3) & 7) << 4)));
}
static __device__ __forceinline__ const ushort* swzp_hi(const ushort* base, int row, int colbyte) {
    return (const ushort*)((const char*)base + row * 128 + (colbyte ^ (((row >> 3) & 7) << 4)));
}
static __device__ __forceinline__ ushort* swzp_lo(ushort* base, int row, int colbyte) {
    return (ushort*)((char*)base + row * 128 + (colbyte ^ ((row & 7) << 4)));
}
static __device__ __forceinline__ const ushort* swzp_lo(const ushort* base, int row, int colbyte) {
    return (const ushort*)((const char*)base + row * 128 + (colbyte ^ ((row & 7) << 4)));
}

#define GLD_LDS(gp, lp) \
    __builtin_amdgcn_global_load_lds( \
        (const __attribute__((address_space(1))) unsigned int*)(gp), \
        (__attribute__((address_space(3))) unsigned int*)(lp), 16, 0, 0)

// ---------------- weight transpose + f32->bf16 ----------------
// in: f32 [K][N] row-major, out: bf16(ushort) [N][K]
__global__ __launch_bounds__(256) void transpose_to_bf16(
    const float* __restrict__ in, ushort* __restrict__ out, int K, int N)
{
    __shared__ float tile[32][33];
    const int k0 = blockIdx.x * 32, n0 = blockIdx.y * 32;
    const int tx = threadIdx.x, ty = threadIdx.y;   // block (32,8)
#pragma unroll
    for (int i = ty; i < 32; i += 8)
        tile[i][tx] = in[(size_t)(k0 + i) * N + n0 + tx];
    __syncthreads();
#pragma unroll
    for (int i = ty; i < 32; i += 8)
        out[(size_t)(n0 + i) * K + k0 + tx] = f2bf(tile[tx][i]);
}

// ---------------- RMSNorm: f32 in -> bf16 out (D=1024, 256 thr/row) ----------------
__global__ __launch_bounds__(256) void rmsnorm_kernel(
    const float* __restrict__ x, const float* __restrict__ g,
    ushort* __restrict__ out, int D)
{
    const int row = blockIdx.x;
    const int tid = threadIdx.x;
    const float4 v = ((const float4*)(x + (size_t)row * D))[tid];
    float ss = v.x * v.x + v.y * v.y + v.z * v.z + v.w * v.w;
#pragma unroll
    for (int off = 32; off > 0; off >>= 1) ss += __shfl_down(ss, off);
    __shared__ float sums[4];
    if ((tid & 63) == 0) sums[tid >> 6] = ss;
    __syncthreads();
    const float tot = sums[0] + sums[1] + sums[2] + sums[3];
    const float scale = rsqrtf(tot / (float)D + 1e-6f);
    const float4 gv = ((const float4*)g)[tid];
    ushort4 o;
    o.x = f2bf(v.x * scale * gv.x);
    o.y = f2bf(v.y * scale * gv.y);
    o.z = f2bf(v.z * scale * gv.z);
    o.w = f2bf(v.w * scale * gv.w);
    *(ushort4*)(out + (size_t)row * D + tid * 4) = o;
}

// ---------------- bf16 GEMM (m97 structure): C = A @ BT^T + bias, epilogue ----
// global_load_lds(16B) staging, linear LDS (gload_lds writes linearly -> reads linear).
// EPI: 0 = bf16 out; 1 = silu -> bf16 out; 2 = +resid -> f32 out; 3 = silu + resid -> f32 out
template <int EPI>
__global__ __launch_bounds__(256) void gemm_bf16_kernel(
    const ushort* __restrict__ A, const ushort* __restrict__ BT,
    const float* __restrict__ bias, const float* __restrict__ resid,
    void* __restrict__ outp, int M, int N, int K)
{
    constexpr int BK = 32;
    __shared__ alignas(16) ushort As[128 * BK];
    __shared__ alignas(16) ushort Bs[128 * BK];
    const int bm = blockIdx.y * 128, bn = blockIdx.x * 128;
    const int tid = threadIdx.x;
    const int lane = tid & 63, wave = tid >> 6;
    const int wr = (wave >> 1) * 64, wc = (wave & 1) * 64;
    const int l15 = lane & 15, l4 = lane >> 4;

    f32x4 acc[4][4] = {};

    // staging: wave w covers tile rows [w*32, w*32+32) via 2 loads of 16 rows.
    // lane l supplies global row +(l>>2), col (l&3)*8; HW writes LDS base + lane*16B.
    const int grow = wave * 32 + (lane >> 2);
    const int gcol = (lane & 3) * 8;
    const ushort* Ag = A + (size_t)(bm + grow) * K + gcol;
    const ushort* Bg = BT + (size_t)(bn + grow) * K + gcol;
    ushort* AsW = As + wave * 32 * BK;
    ushort* BsW = Bs + wave * 32 * BK;

    for (int k0 = 0; k0 < K; k0 += BK) {
        GLD_LDS(Ag + k0, AsW);
        GLD_LDS(Ag + (size_t)16 * K + k0, AsW + 16 * BK);
        GLD_LDS(Bg + k0, BsW);
        GLD_LDS(Bg + (size_t)16 * K + k0, BsW + 16 * BK);
        __syncthreads();

        bf16x8 af[4], bf[4];
#pragma unroll
        for (int mt = 0; mt < 4; ++mt)
            af[mt] = *(const bf16x8*)&As[(wr + mt * 16 + l15) * BK + l4 * 8];
#pragma unroll
        for (int nt = 0; nt < 4; ++nt)
            bf[nt] = *(const bf16x8*)&Bs[(wc + nt * 16 + l15) * BK + l4 * 8];
#pragma unroll
        for (int mt = 0; mt < 4; ++mt)
#pragma unroll
            for (int nt = 0; nt < 4; ++nt)
                acc[mt][nt] = __builtin_amdgcn_mfma_f32_16x16x32_bf16(
                    af[mt], bf[nt], acc[mt][nt], 0, 0, 0);
        __syncthreads();
    }

#pragma unroll
    for (int mt = 0; mt < 4; ++mt) {
#pragma unroll
        for (int nt = 0; nt < 4; ++nt) {
#pragma unroll
            for (int i = 0; i < 4; ++i) {
                const int row = bm + wr + mt * 16 + l4 * 4 + i;
                const int col = bn + wc + nt * 16 + l15;
                float v = acc[mt][nt][i] + bias[col];
                if constexpr (EPI == 1 || EPI == 3) v = v / (1.f + __expf(-v));  // silu
                if constexpr (EPI == 2 || EPI == 3) v += resid[(size_t)row * N + col];
                if constexpr (EPI == 0 || EPI == 1)
                    ((ushort*)outp)[(size_t)row * N + col] = f2bf(v);
                else
                    ((float*)outp)[(size_t)row * N + col] = v;
            }
        }
    }
}

// ---------------- causal flash attention (MLA), 16 heads, HD=64 ----------------
// grid: (S/64, NH); block 256 (4 waves x 16 q-rows). Q,K,V,O bf16 [S][NH*HD]
// Swizzled LDS (kills 16-way conflicts) + reg-prefetch of next KV tile (T14)
// + heavy-qb-first block order.
__global__ __launch_bounds__(256) void mla_attn_kernel(
    const ushort* __restrict__ Q, const ushort* __restrict__ Kg,
    const ushort* __restrict__ Vg, ushort* __restrict__ O)
{
    constexpr int NHHD = TNH * THD;   // 1024
    __shared__ alignas(16) ushort Ks[64 * 64];    // [key][d], hi-swizzled
    __shared__ alignas(16) ushort VTs[64 * 64];   // [d][key], hi-swizzled
    __shared__ alignas(16) ushort Ps[4][16 * 64]; // per-wave [row][key], lo-swizzled
    const int qb = (int)gridDim.x - 1 - (int)blockIdx.x;   // heavy blocks first
    const int h = blockIdx.y;
    const int tid = threadIdx.x, lane = tid & 63, wave = tid >> 6;
    const int l15 = lane & 15, l4 = lane >> 4;
    const int qrow0 = qb * 64 + wave * 16;

    bf16x8 qf[2];
#pragma unroll
    for (int ks = 0; ks < 2; ++ks)
        qf[ks] = *(const bf16x8*)&Q[(size_t)(qrow0 + l15) * NHHD + h * THD + ks * 32 + l4 * 8];

    f32x4 oacc[4] = {};
    float m_run[4], l_run[4];
#pragma unroll
    for (int i = 0; i < 4; ++i) { m_run[i] = -1e30f; l_run[i] = 0.f; }

    const int sr = tid >> 3, sc = (tid & 7) * 8;  // staging coords (32 rows x 64 cols)
    const ushort* kbase = Kg + (size_t)sr * NHHD + h * THD + sc;
    const ushort* vbase = Vg + (size_t)sr * NHHD + h * THD + sc;

    uint4 kr0, kr1, vr0, vr1;
    {   // prefetch tile 0
        kr0 = *(const uint4*)kbase;
        kr1 = *(const uint4*)(kbase + (size_t)32 * NHHD);
        vr0 = *(const uint4*)vbase;
        vr1 = *(const uint4*)(vbase + (size_t)32 * NHHD);
    }

    for (int kt = 0; kt <= qb; ++kt) {
        __syncthreads();   // all waves done reading Ks/VTs of previous tile
        // ---- write K tile (vector, swizzled) ----
        *(uint4*)swzp_hi(Ks, sr, sc * 2) = kr0;
        *(uint4*)swzp_hi(Ks, sr + 32, sc * 2) = kr1;
        // ---- scatter V^T (swizzled: row>>3 varies per-lane -> conflict-free) ----
        {
            const ushort* p0 = (const ushort*)&vr0;
            const ushort* p1 = (const ushort*)&vr1;
#pragma unroll
            for (int j = 0; j < 8; ++j) {
                *swzp_hi(VTs, sc + j, sr * 2) = p0[j];
                *swzp_hi(VTs, sc + j, (sr + 32) * 2) = p1[j];
            }
        }
        __syncthreads();
        // ---- prefetch next tile into regs; latency hides under compute ----
        if (kt < qb) {
            const size_t off = (size_t)(kt + 1) * 64 * NHHD;
            kr0 = *(const uint4*)(kbase + off);
            kr1 = *(const uint4*)(kbase + off + (size_t)32 * NHHD);
            vr0 = *(const uint4*)(vbase + off);
            vr1 = *(const uint4*)(vbase + off + (size_t)32 * NHHD);
        }

        // ---- scores: s[nt] = Q @ K^T  (16 rows x 64 keys) ----
        f32x4 s[4] = {};
#pragma unroll
        for (int ks = 0; ks < 2; ++ks) {
#pragma unroll
            for (int nt = 0; nt < 4; ++nt) {
                const bf16x8 kf = *(const bf16x8*)swzp_hi(Ks, nt * 16 + l15, ks * 64 + l4 * 16);
                s[nt] = __builtin_amdgcn_mfma_f32_16x16x32_bf16(qf[ks], kf, s[nt], 0, 0, 0);
            }
        }

        const int kb = kt * 64;
        const bool diag = (kt == qb);
#pragma unroll
        for (int i = 0; i < 4; ++i) {
            const int qrow = qrow0 + l4 * 4 + i;
            float mx = m_run[i];
#pragma unroll
            for (int nt = 0; nt < 4; ++nt) {
                float v = s[nt][i] * 0.125f;
                if (diag && (kb + nt * 16 + l15 > qrow)) v = -1e30f;
                s[nt][i] = v;
                mx = fmaxf(mx, v);
            }
#pragma unroll
            for (int d = 1; d < 16; d <<= 1) mx = fmaxf(mx, __shfl_xor(mx, d));
            const float alpha = __expf(m_run[i] - mx);
            l_run[i] *= alpha;
#pragma unroll
            for (int nt = 0; nt < 4; ++nt) oacc[nt][i] *= alpha;
            float ps = 0.f;
#pragma unroll
            for (int nt = 0; nt < 4; ++nt) {
                const float p = __expf(s[nt][i] - mx);
                s[nt][i] = p;
                ps += p;
            }
#pragma unroll
            for (int d = 1; d < 16; d <<= 1) ps += __shfl_xor(ps, d);
            l_run[i] += ps;
            m_run[i] = mx;
#pragma unroll
            for (int nt = 0; nt < 4; ++nt)
                *swzp_lo(&Ps[wave][0], l4 * 4 + i, (nt * 16 + l15) * 2) = f2bf(s[nt][i]);
        }

        // ---- PV: oacc += P @ V  (Ps is per-wave: no cross-wave barrier needed) ----
#pragma unroll
        for (int ks = 0; ks < 2; ++ks) {
            const bf16x8 pf = *(const bf16x8*)swzp_lo(&Ps[wave][0], l15, ks * 64 + l4 * 16);
#pragma unroll
            for (int dt = 0; dt < 4; ++dt) {
                const bf16x8 vf = *(const bf16x8*)swzp_hi(VTs, dt * 16 + l15, ks * 64 + l4 * 16);
                oacc[dt] = __builtin_amdgcn_mfma_f32_16x16x32_bf16(pf, vf, oacc[dt], 0, 0, 0);
            }
        }
    }

#pragma unroll
    for (int dt = 0; dt < 4; ++dt)
#pragma unroll
        for (int i = 0; i < 4; ++i) {
            const int qrow = qrow0 + l4 * 4 + i;
            const float v = oacc[dt][i] / l_run[i];
            O[(size_t)qrow * NHHD + h * THD + dt * 16 + l15] = f2bf(v);
        }
}

// ---------------- launch ----------------
extern "C" void kernel_launch(void* const* d_in, const int* in_sizes, int n_in,
                              void* d_out, int out_size, void* d_ws, size_t ws_size,
                              hipStream_t stream)
{
    const float* x     = (const float*)d_in[0];
    const float* g1    = (const float*)d_in[1];
    const float* Wq    = (const float*)d_in[2];
    const float* bq    = (const float*)d_in[3];
    const float* Wdown = (const float*)d_in[4];
    const float* bdown = (const float*)d_in[5];
    const float* Wk    = (const float*)d_in[6];
    const float* bk    = (const float*)d_in[7];
    const float* Wv    = (const float*)d_in[8];
    const float* bv    = (const float*)d_in[9];
    const float* Wo    = (const float*)d_in[10];
    const float* bo    = (const float*)d_in[11];
    const float* g2    = (const float*)d_in[12];
    const float* W1    = (const float*)d_in[13];
    const float* b1    = (const float*)d_in[14];
    const float* W2    = (const float*)d_in[15];
    const float* b2    = (const float*)d_in[16];
    float* out = (float*)d_out;

    char* ws = (char*)d_ws;
    size_t off = 0;
    auto alloc = [&](size_t bytes) {
        void* p = ws + off;
        off += (bytes + 255) & ~(size_t)255;
        return p;
    };
    ushort* WqT    = (ushort*)alloc((size_t)TH * TD * 2);
    ushort* WdownT = (ushort*)alloc((size_t)TL * TD * 2);
    ushort* WkT    = (ushort*)alloc((size_t)TH * TL * 2);
    ushort* WvT    = (ushort*)alloc((size_t)TH * TL * 2);
    ushort* WoT    = (ushort*)alloc((size_t)TD * TH * 2);
    ushort* W1T    = (ushort*)alloc((size_t)TDF * TD * 2);
    ushort* W2T    = (ushort*)alloc((size_t)TD * TDF * 2);
    ushort* hbuf   = (ushort*)alloc((size_t)TS * TD * 2);
    ushort* cbuf   = (ushort*)alloc((size_t)TS * TL * 2);
    ushort* qbuf   = (ushort*)alloc((size_t)TS * TH * 2);
    ushort* kbuf   = (ushort*)alloc((size_t)TS * TH * 2);
    ushort* vbuf   = (ushort*)alloc((size_t)TS * TH * 2);
    ushort* obuf   = (ushort*)alloc((size_t)TS * TH * 2);
    float*  strm   = (float*)alloc((size_t)TS * TD * 4);
    ushort* h2buf  = (ushort*)alloc((size_t)TS * TD * 2);
    ushort* ffn1   = (ushort*)alloc((size_t)TS * TDF * 2);

    const dim3 tb(32, 8);
    transpose_to_bf16<<<dim3(TD / 32, TH / 32), tb, 0, stream>>>(Wq, WqT, TD, TH);
    transpose_to_bf16<<<dim3(TD / 32, TL / 32), tb, 0, stream>>>(Wdown, WdownT, TD, TL);
    transpose_to_bf16<<<dim3(TL / 32, TH / 32), tb, 0, stream>>>(Wk, WkT, TL, TH);
    transpose_to_bf16<<<dim3(TL / 32, TH / 32), tb, 0, stream>>>(Wv, WvT, TL, TH);
    transpose_to_bf16<<<dim3(TH / 32, TD / 32), tb, 0, stream>>>(Wo, WoT, TH, TD);
    transpose_to_bf16<<<dim3(TD / 32, TDF / 32), tb, 0, stream>>>(W1, W1T, TD, TDF);
    transpose_to_bf16<<<dim3(TDF / 32, TD / 32), tb, 0, stream>>>(W2, W2T, TDF, TD);

    rmsnorm_kernel<<<TS, 256, 0, stream>>>(x, g1, hbuf, TD);

    gemm_bf16_kernel<0><<<dim3(TH / 128, TS / 128), 256, 0, stream>>>(
        hbuf, WqT, bq, nullptr, qbuf, TS, TH, TD);
    gemm_bf16_kernel<0><<<dim3(TL / 128, TS / 128), 256, 0, stream>>>(
        hbuf, WdownT, bdown, nullptr, cbuf, TS, TL, TD);
    gemm_bf16_kernel<0><<<dim3(TH / 128, TS / 128), 256, 0, stream>>>(
        cbuf, WkT, bk, nullptr, kbuf, TS, TH, TL);
    gemm_bf16_kernel<0><<<dim3(TH / 128, TS / 128), 256, 0, stream>>>(
        cbuf, WvT, bv, nullptr, vbuf, TS, TH, TL);

    mla_attn_kernel<<<dim3(TS / 64, TNH), 256, 0, stream>>>(qbuf, kbuf, vbuf, obuf);

    gemm_bf16_kernel<2><<<dim3(TD / 128, TS / 128), 256, 0, stream>>>(
        obuf, WoT, bo, x, strm, TS, TD, TH);

    rmsnorm_kernel<<<TS, 256, 0, stream>>>(strm, g2, h2buf, TD);

    gemm_bf16_kernel<1><<<dim3(TDF / 128, TS / 128), 256, 0, stream>>>(
        h2buf, W1T, b1, nullptr, ffn1, TS, TDF, TD);
    gemm_bf16_kernel<3><<<dim3(TD / 128, TS / 128), 256, 0, stream>>>(
        ffn1, W2T, b2, strm, out, TS, TD, TDF);
}

// Round 3
// 258.080 us; speedup vs baseline: 1.4439x; 1.3010x over previous
//
#include <hip/hip_runtime.h>

// ---------------- types ----------------
typedef __bf16 bf16x8 __attribute__((ext_vector_type(8)));
typedef float  f32x4  __attribute__((ext_vector_type(4)));

static __device__ __forceinline__ ushort f2bf(float f) {
    union { float f; unsigned u; } a; a.f = f;
    unsigned r = a.u + 0x7FFFu + ((a.u >> 16) & 1u);   // RNE
    return (ushort)(r >> 16);
}

// ---------------- constants ----------------
#define TS  2048   // S
#define TD  1024   // D
#define TL  256    // L
#define TH  1024   // H
#define TNH 16
#define THD 64
#define TDF 4096   // 4*D

// LDS swizzle helpers for 128-byte-row tiles (attn).
static __device__ __forceinline__ ushort* swzp_hi(ushort* base, int row, int colbyte) {
    return (ushort*)((char*)base + row * 128 + (colbyte ^ (((row >> 3) & 7) << 4)));
}
static __device__ __forceinline__ const ushort* swzp_hi(const ushort* base, int row, int colbyte) {
    return (const ushort*)((const char*)base + row * 128 + (colbyte ^ (((row >> 3) & 7) << 4)));
}
static __device__ __forceinline__ ushort* swzp_lo(ushort* base, int row, int colbyte) {
    return (ushort*)((char*)base + row * 128 + (colbyte ^ ((row & 7) << 4)));
}
static __device__ __forceinline__ const ushort* swzp_lo(const ushort* base, int row, int colbyte) {
    return (const ushort*)((const char*)base + row * 128 + (colbyte ^ ((row & 7) << 4)));
}

#define GLD_LDS(gp, lp) \
    __builtin_amdgcn_global_load_lds( \
        (const __attribute__((address_space(1))) unsigned int*)(gp), \
        (__attribute__((address_space(3))) unsigned int*)(lp), 16, 0, 0)

// ---------------- weight transpose + f32->bf16 ----------------
__global__ __launch_bounds__(256) void transpose_to_bf16(
    const float* __restrict__ in, ushort* __restrict__ out, int K, int N)
{
    __shared__ float tile[32][33];
    const int k0 = blockIdx.x * 32, n0 = blockIdx.y * 32;
    const int tx = threadIdx.x, ty = threadIdx.y;   // block (32,8)
#pragma unroll
    for (int i = ty; i < 32; i += 8)
        tile[i][tx] = in[(size_t)(k0 + i) * N + n0 + tx];
    __syncthreads();
#pragma unroll
    for (int i = ty; i < 32; i += 8)
        out[(size_t)(n0 + i) * K + k0 + tx] = f2bf(tile[tx][i]);
}

// ---------------- RMSNorm: f32 in -> bf16 out ----------------
__global__ __launch_bounds__(256) void rmsnorm_kernel(
    const float* __restrict__ x, const float* __restrict__ g,
    ushort* __restrict__ out, int D)
{
    const int row = blockIdx.x;
    const int tid = threadIdx.x;
    const float4 v = ((const float4*)(x + (size_t)row * D))[tid];
    float ss = v.x * v.x + v.y * v.y + v.z * v.z + v.w * v.w;
#pragma unroll
    for (int off = 32; off > 0; off >>= 1) ss += __shfl_down(ss, off);
    __shared__ float sums[4];
    if ((tid & 63) == 0) sums[tid >> 6] = ss;
    __syncthreads();
    const float tot = sums[0] + sums[1] + sums[2] + sums[3];
    const float scale = rsqrtf(tot / (float)D + 1e-6f);
    const float4 gv = ((const float4*)g)[tid];
    ushort4 o;
    o.x = f2bf(v.x * scale * gv.x);
    o.y = f2bf(v.y * scale * gv.y);
    o.z = f2bf(v.z * scale * gv.z);
    o.w = f2bf(v.w * scale * gv.w);
    *(ushort4*)(out + (size_t)row * D + tid * 4) = o;
}

// ---------------- bf16 GEMM: C = A @ BT^T + bias, epilogue -------------------
// 2-phase double-buffered LDS (stage t+1 before compute t; one vmcnt(0)+barrier
// per step). Templated tile: 64x64 (high occupancy, small-N GEMMs) or 128x128.
// 256 threads, 2x2 wave grid, wave tile (BM/2)x(BN/2).
// EPI: 0 = bf16 out; 1 = silu -> bf16; 2 = +resid -> f32; 3 = silu + resid -> f32
template <int EPI, int BM, int BN>
__global__ __launch_bounds__(256) void gemm_bf16_kernel(
    const ushort* __restrict__ A, const ushort* __restrict__ BT,
    const float* __restrict__ bias, const float* __restrict__ resid,
    void* __restrict__ outp, int M, int N, int K)
{
    constexpr int BK = 32;
    constexpr int WM = BM / 2, WN = BN / 2;
    constexpr int MT = WM / 16, NT = WN / 16;
    constexpr int NLA = BM / 64, NLB = BN / 64;   // gload_lds lines per matrix
    __shared__ alignas(16) ushort As[2][BM * BK];
    __shared__ alignas(16) ushort Bs[2][BN * BK];
    const int bm = blockIdx.y * BM, bn = blockIdx.x * BN;
    const int tid = threadIdx.x;
    const int lane = tid & 63, wave = tid >> 6;
    const int wr = (wave >> 1) * WM, wc = (wave & 1) * WN;
    const int l15 = lane & 15, l4 = lane >> 4;

    f32x4 acc[MT][NT] = {};

    // one gload_lds line: 4 waves x 64 lanes x 16B = 64 rows x 32 cols (bf16)
    const int grow = wave * 16 + (lane >> 2);
    const int gcol = (lane & 3) * 8;
    const ushort* Ag = A + (size_t)(bm + grow) * K + gcol;
    const ushort* Bg = BT + (size_t)(bn + grow) * K + gcol;

    auto stage = [&](int buf, int k0) {
#pragma unroll
        for (int i = 0; i < NLA; ++i)
            GLD_LDS(Ag + (size_t)(i * 64) * K + k0, &As[buf][(i * 64 + wave * 16) * BK]);
#pragma unroll
        for (int i = 0; i < NLB; ++i)
            GLD_LDS(Bg + (size_t)(i * 64) * K + k0, &Bs[buf][(i * 64 + wave * 16) * BK]);
    };

    stage(0, 0);
    asm volatile("s_waitcnt vmcnt(0)" ::: "memory");
    __syncthreads();

    const int nsteps = K / BK;
    for (int t = 0; t < nsteps; ++t) {
        const int cur = t & 1;
        if (t + 1 < nsteps) stage(cur ^ 1, (t + 1) * BK);

        bf16x8 af[MT], bf[NT];
#pragma unroll
        for (int mt = 0; mt < MT; ++mt)
            af[mt] = *(const bf16x8*)&As[cur][(wr + mt * 16 + l15) * BK + l4 * 8];
#pragma unroll
        for (int nt = 0; nt < NT; ++nt)
            bf[nt] = *(const bf16x8*)&Bs[cur][(wc + nt * 16 + l15) * BK + l4 * 8];
#pragma unroll
        for (int mt = 0; mt < MT; ++mt)
#pragma unroll
            for (int nt = 0; nt < NT; ++nt)
                acc[mt][nt] = __builtin_amdgcn_mfma_f32_16x16x32_bf16(
                    af[mt], bf[nt], acc[mt][nt], 0, 0, 0);

        asm volatile("s_waitcnt vmcnt(0)" ::: "memory");
        __syncthreads();
    }

#pragma unroll
    for (int mt = 0; mt < MT; ++mt) {
#pragma unroll
        for (int nt = 0; nt < NT; ++nt) {
#pragma unroll
            for (int i = 0; i < 4; ++i) {
                const int row = bm + wr + mt * 16 + l4 * 4 + i;
                const int col = bn + wc + nt * 16 + l15;
                float v = acc[mt][nt][i] + bias[col];
                if constexpr (EPI == 1 || EPI == 3) v = v / (1.f + __expf(-v));  // silu
                if constexpr (EPI == 2 || EPI == 3) v += resid[(size_t)row * N + col];
                if constexpr (EPI == 0 || EPI == 1)
                    ((ushort*)outp)[(size_t)row * N + col] = f2bf(v);
                else
                    ((float*)outp)[(size_t)row * N + col] = v;
            }
        }
    }
}

// ---------------- causal flash attention (MLA), 16 heads, HD=64 ----------------
__global__ __launch_bounds__(256) void mla_attn_kernel(
    const ushort* __restrict__ Q, const ushort* __restrict__ Kg,
    const ushort* __restrict__ Vg, ushort* __restrict__ O)
{
    constexpr int NHHD = TNH * THD;   // 1024
    __shared__ alignas(16) ushort Ks[64 * 64];    // [key][d], hi-swizzled
    __shared__ alignas(16) ushort VTs[64 * 64];   // [d][key], hi-swizzled
    __shared__ alignas(16) ushort Ps[4][16 * 64]; // per-wave [row][key], lo-swizzled
    const int qb = (int)gridDim.x - 1 - (int)blockIdx.x;   // heavy blocks first
    const int h = blockIdx.y;
    const int tid = threadIdx.x, lane = tid & 63, wave = tid >> 6;
    const int l15 = lane & 15, l4 = lane >> 4;
    const int qrow0 = qb * 64 + wave * 16;

    bf16x8 qf[2];
#pragma unroll
    for (int ks = 0; ks < 2; ++ks)
        qf[ks] = *(const bf16x8*)&Q[(size_t)(qrow0 + l15) * NHHD + h * THD + ks * 32 + l4 * 8];

    f32x4 oacc[4] = {};
    float m_run[4], l_run[4];
#pragma unroll
    for (int i = 0; i < 4; ++i) { m_run[i] = -1e30f; l_run[i] = 0.f; }

    const int sr = tid >> 3, sc = (tid & 7) * 8;  // staging coords (32 rows x 64 cols)
    const ushort* kbase = Kg + (size_t)sr * NHHD + h * THD + sc;
    const ushort* vbase = Vg + (size_t)sr * NHHD + h * THD + sc;

    uint4 kr0, kr1, vr0, vr1;
    {   // prefetch tile 0
        kr0 = *(const uint4*)kbase;
        kr1 = *(const uint4*)(kbase + (size_t)32 * NHHD);
        vr0 = *(const uint4*)vbase;
        vr1 = *(const uint4*)(vbase + (size_t)32 * NHHD);
    }

    for (int kt = 0; kt <= qb; ++kt) {
        __syncthreads();   // all waves done reading Ks/VTs of previous tile
        *(uint4*)swzp_hi(Ks, sr, sc * 2) = kr0;
        *(uint4*)swzp_hi(Ks, sr + 32, sc * 2) = kr1;
        {
            const ushort* p0 = (const ushort*)&vr0;
            const ushort* p1 = (const ushort*)&vr1;
#pragma unroll
            for (int j = 0; j < 8; ++j) {
                *swzp_hi(VTs, sc + j, sr * 2) = p0[j];
                *swzp_hi(VTs, sc + j, (sr + 32) * 2) = p1[j];
            }
        }
        __syncthreads();
        if (kt < qb) {
            const size_t off = (size_t)(kt + 1) * 64 * NHHD;
            kr0 = *(const uint4*)(kbase + off);
            kr1 = *(const uint4*)(kbase + off + (size_t)32 * NHHD);
            vr0 = *(const uint4*)(vbase + off);
            vr1 = *(const uint4*)(vbase + off + (size_t)32 * NHHD);
        }

        // ---- scores: s[nt] = Q @ K^T ----
        f32x4 s[4] = {};
#pragma unroll
        for (int ks = 0; ks < 2; ++ks) {
#pragma unroll
            for (int nt = 0; nt < 4; ++nt) {
                const bf16x8 kf = *(const bf16x8*)swzp_hi(Ks, nt * 16 + l15, ks * 64 + l4 * 16);
                s[nt] = __builtin_amdgcn_mfma_f32_16x16x32_bf16(qf[ks], kf, s[nt], 0, 0, 0);
            }
        }

        const int kb = kt * 64;
        const bool diag = (kt == qb);
#pragma unroll
        for (int i = 0; i < 4; ++i) {
            const int qrow = qrow0 + l4 * 4 + i;
            float mx = m_run[i];
#pragma unroll
            for (int nt = 0; nt < 4; ++nt) {
                float v = s[nt][i] * 0.125f;
                if (diag && (kb + nt * 16 + l15 > qrow)) v = -1e30f;
                s[nt][i] = v;
                mx = fmaxf(mx, v);
            }
#pragma unroll
            for (int d = 1; d < 16; d <<= 1) mx = fmaxf(mx, __shfl_xor(mx, d));
            const float alpha = __expf(m_run[i] - mx);
            l_run[i] *= alpha;
#pragma unroll
            for (int nt = 0; nt < 4; ++nt) oacc[nt][i] *= alpha;
            float ps = 0.f;
#pragma unroll
            for (int nt = 0; nt < 4; ++nt) {
                const float p = __expf(s[nt][i] - mx);
                s[nt][i] = p;
                ps += p;
            }
#pragma unroll
            for (int d = 1; d < 16; d <<= 1) ps += __shfl_xor(ps, d);
            l_run[i] += ps;
            m_run[i] = mx;
#pragma unroll
            for (int nt = 0; nt < 4; ++nt)
                *swzp_lo(&Ps[wave][0], l4 * 4 + i, (nt * 16 + l15) * 2) = f2bf(s[nt][i]);
        }

        // ---- PV ----
#pragma unroll
        for (int ks = 0; ks < 2; ++ks) {
            const bf16x8 pf = *(const bf16x8*)swzp_lo(&Ps[wave][0], l15, ks * 64 + l4 * 16);
#pragma unroll
            for (int dt = 0; dt < 4; ++dt) {
                const bf16x8 vf = *(const bf16x8*)swzp_hi(VTs, dt * 16 + l15, ks * 64 + l4 * 16);
                oacc[dt] = __builtin_amdgcn_mfma_f32_16x16x32_bf16(pf, vf, oacc[dt], 0, 0, 0);
            }
        }
    }

#pragma unroll
    for (int dt = 0; dt < 4; ++dt)
#pragma unroll
        for (int i = 0; i < 4; ++i) {
            const int qrow = qrow0 + l4 * 4 + i;
            const float v = oacc[dt][i] / l_run[i];
            O[(size_t)qrow * NHHD + h * THD + dt * 16 + l15] = f2bf(v);
        }
}

// ---------------- launch ----------------
extern "C" void kernel_launch(void* const* d_in, const int* in_sizes, int n_in,
                              void* d_out, int out_size, void* d_ws, size_t ws_size,
                              hipStream_t stream)
{
    const float* x     = (const float*)d_in[0];
    const float* g1    = (const float*)d_in[1];
    const float* Wq    = (const float*)d_in[2];
    const float* bq    = (const float*)d_in[3];
    const float* Wdown = (const float*)d_in[4];
    const float* bdown = (const float*)d_in[5];
    const float* Wk    = (const float*)d_in[6];
    const float* bk    = (const float*)d_in[7];
    const float* Wv    = (const float*)d_in[8];
    const float* bv    = (const float*)d_in[9];
    const float* Wo    = (const float*)d_in[10];
    const float* bo    = (const float*)d_in[11];
    const float* g2    = (const float*)d_in[12];
    const float* W1    = (const float*)d_in[13];
    const float* b1    = (const float*)d_in[14];
    const float* W2    = (const float*)d_in[15];
    const float* b2    = (const float*)d_in[16];
    float* out = (float*)d_out;

    char* ws = (char*)d_ws;
    size_t off = 0;
    auto alloc = [&](size_t bytes) {
        void* p = ws + off;
        off += (bytes + 255) & ~(size_t)255;
        return p;
    };
    ushort* WqT    = (ushort*)alloc((size_t)TH * TD * 2);
    ushort* WdownT = (ushort*)alloc((size_t)TL * TD * 2);
    ushort* WkT    = (ushort*)alloc((size_t)TH * TL * 2);
    ushort* WvT    = (ushort*)alloc((size_t)TH * TL * 2);
    ushort* WoT    = (ushort*)alloc((size_t)TD * TH * 2);
    ushort* W1T    = (ushort*)alloc((size_t)TDF * TD * 2);
    ushort* W2T    = (ushort*)alloc((size_t)TD * TDF * 2);
    ushort* hbuf   = (ushort*)alloc((size_t)TS * TD * 2);
    ushort* cbuf   = (ushort*)alloc((size_t)TS * TL * 2);
    ushort* qbuf   = (ushort*)alloc((size_t)TS * TH * 2);
    ushort* kbuf   = (ushort*)alloc((size_t)TS * TH * 2);
    ushort* vbuf   = (ushort*)alloc((size_t)TS * TH * 2);
    ushort* obuf   = (ushort*)alloc((size_t)TS * TH * 2);
    float*  strm   = (float*)alloc((size_t)TS * TD * 4);
    ushort* h2buf  = (ushort*)alloc((size_t)TS * TD * 2);
    ushort* ffn1   = (ushort*)alloc((size_t)TS * TDF * 2);

    const dim3 tb(32, 8);
    transpose_to_bf16<<<dim3(TD / 32, TH / 32), tb, 0, stream>>>(Wq, WqT, TD, TH);
    transpose_to_bf16<<<dim3(TD / 32, TL / 32), tb, 0, stream>>>(Wdown, WdownT, TD, TL);
    transpose_to_bf16<<<dim3(TL / 32, TH / 32), tb, 0, stream>>>(Wk, WkT, TL, TH);
    transpose_to_bf16<<<dim3(TL / 32, TH / 32), tb, 0, stream>>>(Wv, WvT, TL, TH);
    transpose_to_bf16<<<dim3(TH / 32, TD / 32), tb, 0, stream>>>(Wo, WoT, TH, TD);
    transpose_to_bf16<<<dim3(TD / 32, TDF / 32), tb, 0, stream>>>(W1, W1T, TD, TDF);
    transpose_to_bf16<<<dim3(TDF / 32, TD / 32), tb, 0, stream>>>(W2, W2T, TDF, TD);

    rmsnorm_kernel<<<TS, 256, 0, stream>>>(x, g1, hbuf, TD);

    gemm_bf16_kernel<0, 64, 64><<<dim3(TH / 64, TS / 64), 256, 0, stream>>>(
        hbuf, WqT, bq, nullptr, qbuf, TS, TH, TD);
    gemm_bf16_kernel<0, 64, 64><<<dim3(TL / 64, TS / 64), 256, 0, stream>>>(
        hbuf, WdownT, bdown, nullptr, cbuf, TS, TL, TD);
    gemm_bf16_kernel<0, 64, 64><<<dim3(TH / 64, TS / 64), 256, 0, stream>>>(
        cbuf, WkT, bk, nullptr, kbuf, TS, TH, TL);
    gemm_bf16_kernel<0, 64, 64><<<dim3(TH / 64, TS / 64), 256, 0, stream>>>(
        cbuf, WvT, bv, nullptr, vbuf, TS, TH, TL);

    mla_attn_kernel<<<dim3(TS / 64, TNH), 256, 0, stream>>>(qbuf, kbuf, vbuf, obuf);

    gemm_bf16_kernel<2, 64, 64><<<dim3(TD / 64, TS / 64), 256, 0, stream>>>(
        obuf, WoT, bo, x, strm, TS, TD, TH);

    rmsnorm_kernel<<<TS, 256, 0, stream>>>(strm, g2, h2buf, TD);

    gemm_bf16_kernel<1, 128, 128><<<dim3(TDF / 128, TS / 128), 256, 0, stream>>>(
        h2buf, W1T, b1, nullptr, ffn1, TS, TDF, TD);
    gemm_bf16_kernel<3, 64, 64><<<dim3(TD / 64, TS / 64), 256, 0, stream>>>(
        ffn1, W2T, b2, strm, out, TS, TD, TDF);
}